// Round 8
// baseline (1026.260 us; speedup 1.0000x reference)
//
#include <hip/hip_runtime.h>
#include <hip/hip_bf16.h>

#define TT 4096
#define CC 3072
#define HH 24
#define DD 128

typedef __bf16 bf16;
typedef __attribute__((ext_vector_type(8))) __bf16 bf16x8;
typedef __attribute__((ext_vector_type(4))) __bf16 bf16x4;
typedef __attribute__((ext_vector_type(4))) float f32x4;
typedef __attribute__((ext_vector_type(16))) float f32x16;
typedef __attribute__((ext_vector_type(4))) unsigned uint32x4;

#define MFMA(a,b,c)   __builtin_amdgcn_mfma_f32_16x16x32_bf16((a),(b),(c),0,0,0)
#define MFMA32(a,b,c) __builtin_amdgcn_mfma_f32_32x32x16_bf16((a),(b),(c),0,0,0)

// v_cvt_pk_bf16_f32: low16 = bf16(lo), high16 = bf16(hi)
static __device__ __forceinline__ unsigned cvtpk(float lo, float hi) {
  unsigned r;
  asm("v_cvt_pk_bf16_f32 %0, %1, %2" : "=v"(r) : "v"(lo), "v"(hi));
  return r;
}
static __device__ __forceinline__ float max3f(float a, float b, float c) {
  float r;
  asm("v_max3_f32 %0, %1, %2, %3" : "=v"(r) : "v"(a), "v"(b), "v"(c));
  return r;
}
// v_permlane32_swap_b32: after, x = {x[0:31], y[0:31]}, y = {x[32:63], y[32:63]}
static __device__ __forceinline__ void plswap(unsigned &x, unsigned &y) {
  asm volatile("v_permlane32_swap_b32 %0, %1" : "+v"(x), "+v"(y));
}
// async global->LDS DMA, 16B/lane; LDS dest = wave-uniform base + lane*16 (m97 pattern)
static __device__ __forceinline__ void gl16(const bf16* g, bf16* l) {
  __builtin_amdgcn_global_load_lds(
      (const __attribute__((address_space(1))) unsigned int*)(g),
      (__attribute__((address_space(3))) unsigned int*)(l), 16, 0, 0);
}

// ---------------- f32 -> bf16 convert (vectorized, grid-stride) ----------------
__global__ __launch_bounds__(256)
void cvt_bf16(const float* __restrict__ in, bf16* __restrict__ out, int n8) {
  int i = blockIdx.x * 256 + threadIdx.x;
  const int stride = gridDim.x * 256;
  for (; i < n8; i += stride) {
    const float4* p = (const float4*)(in + (size_t)i * 8);
    float4 a = p[0], b = p[1];
    bf16x8 o;
    o[0]=(bf16)a.x; o[1]=(bf16)a.y; o[2]=(bf16)a.z; o[3]=(bf16)a.w;
    o[4]=(bf16)b.x; o[5]=(bf16)b.y; o[6]=(bf16)b.z; o[7]=(bf16)b.w;
    *(bf16x8*)(out + (size_t)i * 8) = o;
  }
}

// ---------------- GEMM (bf16 inputs, m97 DMA staging): C = A[M][K] @ B[N][K]^T ----------------
template<int OBF>
__global__ __launch_bounds__(256, 2)
void gemm_bt(const bf16* __restrict__ A, const bf16* __restrict__ B,
             void* __restrict__ Cp, int M, int N, int K) {
  __shared__ bf16 As[128 * 32];   // linear row-major [128][32], 64B rows
  __shared__ bf16 Bs[128 * 32];
  const int tid = threadIdx.x, lane = tid & 63, wid = tid >> 6;
  const int m0 = blockIdx.y * 128, n0 = blockIdx.x * 128;
  const int wr = (wid >> 1) * 64, wc = (wid & 1) * 64;
  const int r = lane & 15, g = lane >> 4;
  const int srow = lane >> 2, scol = (lane & 3) * 8;   // lane's slot in a 16-row stripe

  f32x4 acc[4][4] = {};
  const int NT = K >> 5;

  for (int kt = 0; kt < NT; ++kt) {
    const int kk = kt << 5;
    if (kt) __syncthreads();                 // all waves done reading tile kt-1
    #pragma unroll
    for (int j = 0; j < 2; ++j) {            // per wave: 2 A-stripes + 2 B-stripes (1KB each)
      const int base = (wid * 2 + j) * 16;   // stripe = 16 rows x 64B
      gl16(A + (size_t)(m0 + base + srow) * K + kk + scol, As + base * 32);
      gl16(B + (size_t)(n0 + base + srow) * K + kk + scol, Bs + base * 32);
    }
    __syncthreads();                         // implicit vmcnt(0): DMA complete + visible

    bf16x8 af[4], bfr[4];
    #pragma unroll
    for (int m = 0; m < 4; ++m) af[m]  = *(const bf16x8*)&As[(wr + m*16 + r)*32 + g*8];
    #pragma unroll
    for (int n = 0; n < 4; ++n) bfr[n] = *(const bf16x8*)&Bs[(wc + n*16 + r)*32 + g*8];
    #pragma unroll
    for (int m = 0; m < 4; ++m)
      #pragma unroll
      for (int n = 0; n < 4; ++n)
        acc[m][n] = MFMA(af[m], bfr[n], acc[m][n]);
  }

  #pragma unroll
  for (int m = 0; m < 4; ++m)
    #pragma unroll
    for (int n = 0; n < 4; ++n) {
      const int col = n0 + wc + n*16 + r;
      #pragma unroll
      for (int j = 0; j < 4; ++j) {
        const int row = m0 + wr + m*16 + g*4 + j;
        float v = acc[m][n][j];
        if constexpr (OBF) ((bf16*)Cp)[(size_t)row*N + col] = (bf16)v;
        else               ((float*)Cp)[(size_t)row*N + col] = v;
      }
    }
}

// ---------------- legacy GEMM (f32 inputs, reg-staged): fallback if ws too small ----------------
template<int ABF, int OBF>
__global__ __launch_bounds__(256, 2)
void gemm_nt(const void* __restrict__ Ap, const float* __restrict__ Bp,
             void* __restrict__ Cp, int M, int N, int K) {
  __shared__ bf16 As[2][128][40];
  __shared__ bf16 Bs[2][128][40];
  const int tid = threadIdx.x;
  const int lane = tid & 63, wid = tid >> 6;
  const int m0 = blockIdx.y * 128, n0 = blockIdx.x * 128;
  const int wr = (wid >> 1) * 64, wc = (wid & 1) * 64;
  const int r = lane & 15, g = lane >> 4;
  const float* Af = (const float*)Ap;
  const bf16*  Ab = (const bf16*)Ap;

  f32x4 acc[4][4] = {};
  f32x4 pa[4], pb[4];
  bf16x8 qa[2];
  const int NT = K >> 5;

  auto load_tiles = [&](int kt) {
    const int kk = kt * 32;
    if constexpr (ABF) {
      #pragma unroll
      for (int j = 0; j < 2; ++j) {
        int c = tid + 256*j, row = c >> 2, kc = c & 3;
        qa[j] = *(const bf16x8*)(Ab + (size_t)(m0+row)*K + kk + kc*8);
      }
    } else {
      #pragma unroll
      for (int j = 0; j < 4; ++j) {
        int c = tid + 256*j, row = c >> 3, kc = c & 7;
        pa[j] = *(const f32x4*)(Af + (size_t)(m0+row)*K + kk + kc*4);
      }
    }
    #pragma unroll
    for (int j = 0; j < 4; ++j) {
      int c = tid + 256*j, row = c >> 3, kc = c & 7;
      pb[j] = *(const f32x4*)(Bp + (size_t)(n0+row)*K + kk + kc*4);
    }
  };
  auto write_tiles = [&](int buf) {
    if constexpr (ABF) {
      #pragma unroll
      for (int j = 0; j < 2; ++j) {
        int c = tid + 256*j, row = c >> 2, kc = c & 3;
        *(bf16x8*)&As[buf][row][kc*8] = qa[j];
      }
    } else {
      #pragma unroll
      for (int j = 0; j < 4; ++j) {
        int c = tid + 256*j, row = c >> 3, kc = c & 7;
        bf16x4 b;
        b[0]=(bf16)pa[j][0]; b[1]=(bf16)pa[j][1]; b[2]=(bf16)pa[j][2]; b[3]=(bf16)pa[j][3];
        *(bf16x4*)&As[buf][row][kc*4] = b;
      }
    }
    #pragma unroll
    for (int j = 0; j < 4; ++j) {
      int c = tid + 256*j, row = c >> 3, kc = c & 7;
      bf16x4 b;
      b[0]=(bf16)pb[j][0]; b[1]=(bf16)pb[j][1]; b[2]=(bf16)pb[j][2]; b[3]=(bf16)pb[j][3];
      *(bf16x4*)&Bs[buf][row][kc*4] = b;
    }
  };

  load_tiles(0);
  write_tiles(0);
  __syncthreads();
  for (int kt = 0; kt < NT; ++kt) {
    const int cur = kt & 1;
    if (kt + 1 < NT) load_tiles(kt + 1);
    bf16x8 af[4], bfr[4];
    #pragma unroll
    for (int m = 0; m < 4; ++m) af[m]  = *(const bf16x8*)&As[cur][wr + m*16 + r][g*8];
    #pragma unroll
    for (int n = 0; n < 4; ++n) bfr[n] = *(const bf16x8*)&Bs[cur][wc + n*16 + r][g*8];
    #pragma unroll
    for (int m = 0; m < 4; ++m)
      #pragma unroll
      for (int n = 0; n < 4; ++n)
        acc[m][n] = MFMA(af[m], bfr[n], acc[m][n]);
    if (kt + 1 < NT) write_tiles((kt + 1) & 1);
    __syncthreads();
  }
  #pragma unroll
  for (int m = 0; m < 4; ++m)
    #pragma unroll
    for (int n = 0; n < 4; ++n) {
      const int col = n0 + wc + n*16 + r;
      #pragma unroll
      for (int j = 0; j < 4; ++j) {
        const int row = m0 + wr + m*16 + g*4 + j;
        float v = acc[m][n][j];
        if constexpr (OBF) ((bf16*)Cp)[(size_t)row*N + col] = (bf16)v;
        else               ((float*)Cp)[(size_t)row*N + col] = v;
      }
    }
}

// ---------------- RoPE (interleaved pairs), scale folded in ----------------
__global__ __launch_bounds__(256)
void rope_kernel(bf16* __restrict__ X, const float* __restrict__ F, float scale) {
  const int i = blockIdx.x * 256 + threadIdx.x;
  const size_t e8 = (size_t)i * 8;
  const int t  = (int)(e8 / CC);
  const int c  = (int)(e8 % CC);
  const int hc = c & (DD - 1);
  const float4* f = (const float4*)(F + (size_t)t*256 + (hc>>1)*4);
  bf16x8 v = *(const bf16x8*)(X + e8);
  bf16x8 o;
  #pragma unroll
  for (int p = 0; p < 4; ++p) {
    float x0 = (float)v[2*p], x1 = (float)v[2*p+1];
    float4 ff = f[p];
    o[2*p]   = (bf16)((ff.x*x0 + ff.y*x1) * scale);
    o[2*p+1] = (bf16)((ff.z*x0 + ff.w*x1) * scale);
  }
  *(bf16x8*)(X + e8) = o;
}

// ---------------- V [T][C] -> Vt [H][D][T] per-head transpose ----------------
__global__ __launch_bounds__(256)
void transpose_v(const bf16* __restrict__ V, bf16* __restrict__ Vt) {
  __shared__ bf16 tile[64 * 128];
  const int t0 = blockIdx.x * 64, h = blockIdx.y;
  const int tid = threadIdx.x;
  #pragma unroll
  for (int j = 0; j < 4; ++j) {
    int c = tid + 256*j, t = c >> 4, c16 = c & 15;
    uint4 val = *(const uint4*)(V + (size_t)(t0+t)*CC + h*DD + c16*8);
    int sw = ((t & 7) ^ ((t >> 3) & 7)) << 4;
    *(uint4*)((char*)tile + t*256 + ((c16*16) ^ sw)) = val;
  }
  __syncthreads();
  #pragma unroll
  for (int j = 0; j < 4; ++j) {
    int c = tid + 256*j, d = c >> 3, c8 = c & 7;
    bf16x8 o;
    #pragma unroll
    for (int i = 0; i < 8; ++i) {
      int t = c8*8 + i;
      int sw = ((t & 7) ^ ((t >> 3) & 7)) << 4;
      o[i] = *(const bf16*)((char*)tile + t*256 + ((d*2) ^ sw));
    }
    *(bf16x8*)(Vt + (size_t)(h*DD + d)*TT + t0 + c8*8) = o;
  }
}

// ---------------- Flash attention, swapped-QK 32x32, exp2 softmax, async-STAGE ----------------
// Block = 4 waves x 32 q-rows = 128 q-rows, one head. KVBLK = 64.
// Q pre-scaled by log2(e)/sqrt(D). K [T][C]; Vt [H][D][T]. O [T][C].
// T14 split: issue global loads for t+1 BEFORE compute(t); LDS-write after the barrier.
__global__ __launch_bounds__(256, 3)
void attn_kernel(const bf16* __restrict__ Q, const bf16* __restrict__ Kb,
                 const bf16* __restrict__ Vt, bf16* __restrict__ O) {
  __shared__ bf16 Ks[64 * 128];   // [kv][d], 256B rows, 16-slot XOR swizzle
  __shared__ bf16 Vs[128 * 64];   // [d][kv], 128B rows, 8-slot XOR swizzle

  const int tid = threadIdx.x, lane = tid & 63, wid = tid >> 6;
  const int c31 = lane & 31, g2 = lane >> 5;

  const int bid = blockIdx.x;
  const int fid = (bid & 7) * 96 + (bid >> 3);
  const int h = fid >> 5, qt = fid & 31;
  const int qrow = qt * 128 + wid * 32 + c31;

  bf16x8 aq[8];
  {
    const bf16* qp = Q + (size_t)qrow * CC + h * DD + g2 * 8;
    #pragma unroll
    for (int d0 = 0; d0 < 8; ++d0) aq[d0] = *(const bf16x8*)(qp + d0 * 16);
  }

  float m_ = -1e30f, l_ = 0.f;
  f32x16 o_[4] = {};

  uint4 kr[4], vr4[4];
  auto issue = [&](int kv0) {
    #pragma unroll
    for (int j = 0; j < 4; ++j) {
      int cc = tid + 256*j, row = cc >> 4, c16 = cc & 15;
      kr[j] = *(const uint4*)(Kb + (size_t)(kv0 + row) * CC + h * DD + c16 * 8);
    }
    #pragma unroll
    for (int j = 0; j < 4; ++j) {
      int cc = tid + 256*j, row = cc >> 3, c8 = cc & 7;
      vr4[j] = *(const uint4*)(Vt + (size_t)(h * DD + row) * TT + kv0 + c8 * 8);
    }
  };
  auto write_lds = [&]() {
    #pragma unroll
    for (int j = 0; j < 4; ++j) {
      int cc = tid + 256*j, row = cc >> 4, c16 = cc & 15;
      *(uint4*)((char*)Ks + row * 256 + ((c16 * 16) ^ ((row & 15) << 4))) = kr[j];
    }
    #pragma unroll
    for (int j = 0; j < 4; ++j) {
      int cc = tid + 256*j, row = cc >> 3, c8 = cc & 7;
      *(uint4*)((char*)Vs + row * 128 + ((c8 * 16) ^ ((row & 7) << 4))) = vr4[j];
    }
  };

  issue(0);

  const int NT = TT / 64;
  for (int t = 0; t < NT; ++t) {
    if (t) __syncthreads();        // all waves done reading tile t-1
    write_lds();                   // waits on this wave's loads, then ds_write
    __syncthreads();               // tile t visible
    if (t + 1 < NT) issue((t + 1) * 64);   // HBM latency hides under compute

    // S^T = K . Q^T : s[tt][reg] = S[kv = 32tt + (reg&3)+8*(reg>>2)+4*g2][q = c31]
    f32x16 s[2] = {};
    __builtin_amdgcn_s_setprio(1);
    #pragma unroll
    for (int d0 = 0; d0 < 8; ++d0) {
      #pragma unroll
      for (int tt = 0; tt < 2; ++tt) {
        const int kvr = tt * 32 + c31;
        bf16x8 ak = *(const bf16x8*)((const char*)Ks + kvr * 256 +
                                     ((d0 * 32 + g2 * 16) ^ ((kvr & 15) << 4)));
        s[tt] = MFMA32(ak, aq[d0], s[tt]);
      }
    }
    __builtin_amdgcn_s_setprio(0);

    // ---- online softmax (log2 domain), one q-row per lane (partner = lane^32) ----
    float mx = fmaxf(s[0][0], s[0][1]);
    #pragma unroll
    for (int i = 2; i < 16; i += 2) mx = max3f(mx, s[0][i], s[0][i+1]);
    #pragma unroll
    for (int i = 0; i < 16; i += 2) mx = max3f(mx, s[1][i], s[1][i+1]);
    mx = fmaxf(mx, __shfl_xor(mx, 32, 64));
    if (!__all(mx <= m_ + 8.f)) {              // defer-max, THR=8 (log2 units)
      float mn = fmaxf(m_, mx);
      float al = __builtin_amdgcn_exp2f(m_ - mn);
      l_ *= al;
      #pragma unroll
      for (int d0 = 0; d0 < 4; ++d0) o_[d0] *= al;
      m_ = mn;
    }

    // P = exp2(S - m), packed to bf16 pairs via v_cvt_pk_bf16_f32.
    unsigned w0[8], w1[8];
    float rs = 0.f;
    #pragma unroll
    for (int jj = 0; jj < 8; ++jj) {
      float a0 = __builtin_amdgcn_exp2f(s[0][2*jj] - m_);
      float b0 = __builtin_amdgcn_exp2f(s[0][2*jj+1] - m_);
      float a1 = __builtin_amdgcn_exp2f(s[1][2*jj] - m_);
      float b1 = __builtin_amdgcn_exp2f(s[1][2*jj+1] - m_);
      rs += (a0 + b0) + (a1 + b1);
      w0[jj] = cvtpk(a0, b0);
      w1[jj] = cvtpk(a1, b1);
    }
    rs += __shfl_xor(rs, 32, 64);
    l_ += rs;

    // Redistribute P into PV B-fragments via permlane32_swap (no LDS).
    bf16x8 pb[4];
    #pragma unroll
    for (int t2 = 0; t2 < 4; ++t2) {
      const int jA = (t2 & 1) * 4;
      unsigned x0, y0, x1, y1;
      if (t2 < 2) { x0 = w0[jA]; y0 = w0[jA+2]; x1 = w0[jA+1]; y1 = w0[jA+3]; }
      else        { x0 = w1[jA]; y0 = w1[jA+2]; x1 = w1[jA+1]; y1 = w1[jA+3]; }
      plswap(x0, y0);
      plswap(x1, y1);
      uint32x4 uu; uu[0] = x0; uu[1] = x1; uu[2] = y0; uu[3] = y1;
      pb[t2] = __builtin_bit_cast(bf16x8, uu);
    }

    // O^T += V^T . P^T
    __builtin_amdgcn_s_setprio(1);
    #pragma unroll
    for (int d0 = 0; d0 < 4; ++d0) {
      const int vr = d0 * 32 + c31;
      #pragma unroll
      for (int t2 = 0; t2 < 4; ++t2) {
        bf16x8 av = *(const bf16x8*)((const char*)Vs + vr * 128 +
                                     ((t2 * 32 + g2 * 16) ^ ((vr & 7) << 4)));
        o_[d0] = MFMA32(av, pb[t2], o_[d0]);
      }
    }
    __builtin_amdgcn_s_setprio(0);
  }

  const float inv = 1.f / l_;
  bf16* orow = O + (size_t)qrow * CC + h * DD;
  #pragma unroll
  for (int d0 = 0; d0 < 4; ++d0)
    #pragma unroll
    for (int q4 = 0; q4 < 4; ++q4) {
      uint2 val;
      val.x = cvtpk(o_[d0][q4*4 + 0] * inv, o_[d0][q4*4 + 1] * inv);
      val.y = cvtpk(o_[d0][q4*4 + 2] * inv, o_[d0][q4*4 + 3] * inv);
      *(uint2*)(orow + d0*32 + q4*8 + g2*4) = val;
    }
}

// ---------------- host ----------------
extern "C" void kernel_launch(void* const* d_in, const int* in_sizes, int n_in,
                              void* d_out, int out_size, void* d_ws, size_t ws_size,
                              hipStream_t stream) {
  const float* x   = (const float*)d_in[0];
  const float* ctx = (const float*)d_in[1];
  const float* fr  = (const float*)d_in[2];
  const float* Wq  = (const float*)d_in[3];
  const float* Wk  = (const float*)d_in[4];
  const float* Wv  = (const float*)d_in[5];
  const float* Wo  = (const float*)d_in[6];
  float* out = (float*)d_out;
  char* ws = (char*)d_ws;

  const size_t SZ  = (size_t)TT * CC * sizeof(bf16);   // 25,165,824
  const size_t WSZ = (size_t)CC * CC * sizeof(bf16);   // 18,874,368
  bf16* Qb  = (bf16*)(ws);
  bf16* Kbf = (bf16*)(ws + SZ);
  bf16* Vb  = (bf16*)(ws + 2*SZ);
  bf16* Vtb = (bf16*)(ws + 3*SZ);
  bf16* Ob  = Vb;                        // attn output overwrites V (dead after transpose)

  const int rblocks = (TT*CC/8)/256;
  const float QSCALE = 0.12751743314942355f;  // log2(e)/sqrt(128)

  const size_t NEED = 5*SZ + 3*WSZ;      // 182.5 MB
  if (ws_size >= NEED) {
    bf16* xb   = Vtb;                    // x dead after Q-gemm; Vtb written later
    bf16* ctxb = (bf16*)(ws + 4*SZ);
    bf16* Wqb  = (bf16*)(ws + 5*SZ);     // reused for Wo after Q-gemm
    bf16* Wkb  = (bf16*)(ws + 5*SZ + WSZ);
    bf16* Wvb  = (bf16*)(ws + 5*SZ + 2*WSZ);
    bf16* Wob  = Wqb;

    cvt_bf16<<<2048, 256, 0, stream>>>(x,   xb,   TT*CC/8);
    cvt_bf16<<<2048, 256, 0, stream>>>(ctx, ctxb, TT*CC/8);
    cvt_bf16<<<2048, 256, 0, stream>>>(Wq,  Wqb,  CC*CC/8);
    cvt_bf16<<<2048, 256, 0, stream>>>(Wk,  Wkb,  CC*CC/8);
    cvt_bf16<<<2048, 256, 0, stream>>>(Wv,  Wvb,  CC*CC/8);

    dim3 gg(CC/128, TT/128);
    gemm_bt<1><<<gg, 256, 0, stream>>>(xb,   Wqb, Qb,  TT, CC, CC);
    gemm_bt<1><<<gg, 256, 0, stream>>>(ctxb, Wkb, Kbf, TT, CC, CC);
    gemm_bt<1><<<gg, 256, 0, stream>>>(ctxb, Wvb, Vb,  TT, CC, CC);

    rope_kernel<<<rblocks, 256, 0, stream>>>(Qb,  fr, QSCALE);
    rope_kernel<<<rblocks, 256, 0, stream>>>(Kbf, fr, 1.0f);

    transpose_v<<<dim3(TT/64, HH), 256, 0, stream>>>(Vb, Vtb);   // overwrites xb (dead)
    cvt_bf16<<<2048, 256, 0, stream>>>(Wo, Wob, CC*CC/8);        // into Wqb slot (dead)
    attn_kernel<<<dim3(768), 256, 0, stream>>>(Qb, Kbf, Vtb, Ob);

    gemm_bt<0><<<gg, 256, 0, stream>>>(Ob, Wob, out, TT, CC, CC);
  } else {
    // fallback: R7 path (f32 reg-staged GEMMs), ws usage 4*SZ
    dim3 gg(CC/128, TT/128);
    gemm_nt<0,1><<<gg, 256, 0, stream>>>(x,   Wq, Qb,  TT, CC, CC);
    gemm_nt<0,1><<<gg, 256, 0, stream>>>(ctx, Wk, Kbf, TT, CC, CC);
    gemm_nt<0,1><<<gg, 256, 0, stream>>>(ctx, Wv, Vb,  TT, CC, CC);
    rope_kernel<<<rblocks, 256, 0, stream>>>(Qb,  fr, QSCALE);
    rope_kernel<<<rblocks, 256, 0, stream>>>(Kbf, fr, 1.0f);
    transpose_v<<<dim3(TT/64, HH), 256, 0, stream>>>(Vb, Vtb);
    attn_kernel<<<dim3(768), 256, 0, stream>>>(Qb, Kbf, Vtb, Ob);
    gemm_nt<1,0><<<gg, 256, 0, stream>>>(Ob, Wo, out, TT, CC, CC);
  }
}

// Round 9
// 731.820 us; speedup vs baseline: 1.4023x; 1.4023x over previous
//
#include <hip/hip_runtime.h>
#include <hip/hip_bf16.h>

#define TT 4096
#define CC 3072
#define HH 24
#define DD 128

typedef __bf16 bf16;
typedef __attribute__((ext_vector_type(8))) __bf16 bf16x8;
typedef __attribute__((ext_vector_type(4))) __bf16 bf16x4;
typedef __attribute__((ext_vector_type(4))) float f32x4;
typedef __attribute__((ext_vector_type(16))) float f32x16;
typedef __attribute__((ext_vector_type(4))) unsigned uint32x4;

#define MFMA(a,b,c)   __builtin_amdgcn_mfma_f32_16x16x32_bf16((a),(b),(c),0,0,0)
#define MFMA32(a,b,c) __builtin_amdgcn_mfma_f32_32x32x16_bf16((a),(b),(c),0,0,0)

// v_cvt_pk_bf16_f32: low16 = bf16(lo), high16 = bf16(hi)
static __device__ __forceinline__ unsigned cvtpk(float lo, float hi) {
  unsigned r;
  asm("v_cvt_pk_bf16_f32 %0, %1, %2" : "=v"(r) : "v"(lo), "v"(hi));
  return r;
}
static __device__ __forceinline__ float max3f(float a, float b, float c) {
  float r;
  asm("v_max3_f32 %0, %1, %2, %3" : "=v"(r) : "v"(a), "v"(b), "v"(c));
  return r;
}
// v_permlane32_swap_b32: after, x = {x[0:31], y[0:31]}, y = {x[32:63], y[32:63]}
static __device__ __forceinline__ void plswap(unsigned &x, unsigned &y) {
  asm volatile("v_permlane32_swap_b32 %0, %1" : "+v"(x), "+v"(y));
}
// async global->LDS DMA, 16B/lane; LDS dest = wave-uniform base + lane*16 (m97 pattern)
static __device__ __forceinline__ void gl16(const bf16* g, bf16* l) {
  __builtin_amdgcn_global_load_lds(
      (const __attribute__((address_space(1))) unsigned int*)(g),
      (__attribute__((address_space(3))) unsigned int*)(l), 16, 0, 0);
}

// ---------------- f32 -> bf16 convert (vectorized, grid-stride) ----------------
__global__ __launch_bounds__(256)
void cvt_bf16(const float* __restrict__ in, bf16* __restrict__ out, int n8) {
  int i = blockIdx.x * 256 + threadIdx.x;
  const int stride = gridDim.x * 256;
  for (; i < n8; i += stride) {
    const float4* p = (const float4*)(in + (size_t)i * 8);
    float4 a = p[0], b = p[1];
    bf16x8 o;
    o[0]=(bf16)a.x; o[1]=(bf16)a.y; o[2]=(bf16)a.z; o[3]=(bf16)a.w;
    o[4]=(bf16)b.x; o[5]=(bf16)b.y; o[6]=(bf16)b.z; o[7]=(bf16)b.w;
    *(bf16x8*)(out + (size_t)i * 8) = o;
  }
}

// ---------------- GEMM (bf16 inputs, m97 DMA staging): C = A[M][K] @ B[N][K]^T ----------------
template<int OBF>
__global__ __launch_bounds__(256, 2)
void gemm_bt(const bf16* __restrict__ A, const bf16* __restrict__ B,
             void* __restrict__ Cp, int M, int N, int K) {
  __shared__ bf16 As[128 * 32];   // linear row-major [128][32], 64B rows
  __shared__ bf16 Bs[128 * 32];
  const int tid = threadIdx.x, lane = tid & 63, wid = tid >> 6;
  const int m0 = blockIdx.y * 128, n0 = blockIdx.x * 128;
  const int wr = (wid >> 1) * 64, wc = (wid & 1) * 64;
  const int r = lane & 15, g = lane >> 4;
  const int srow = lane >> 2, scol = (lane & 3) * 8;   // lane's slot in a 16-row stripe

  f32x4 acc[4][4] = {};
  const int NT = K >> 5;

  for (int kt = 0; kt < NT; ++kt) {
    const int kk = kt << 5;
    if (kt) __syncthreads();                 // all waves done reading tile kt-1
    #pragma unroll
    for (int j = 0; j < 2; ++j) {            // per wave: 2 A-stripes + 2 B-stripes (1KB each)
      const int base = (wid * 2 + j) * 16;   // stripe = 16 rows x 64B
      gl16(A + (size_t)(m0 + base + srow) * K + kk + scol, As + base * 32);
      gl16(B + (size_t)(n0 + base + srow) * K + kk + scol, Bs + base * 32);
    }
    __syncthreads();                         // implicit vmcnt(0): DMA complete + visible

    bf16x8 af[4], bfr[4];
    #pragma unroll
    for (int m = 0; m < 4; ++m) af[m]  = *(const bf16x8*)&As[(wr + m*16 + r)*32 + g*8];
    #pragma unroll
    for (int n = 0; n < 4; ++n) bfr[n] = *(const bf16x8*)&Bs[(wc + n*16 + r)*32 + g*8];
    #pragma unroll
    for (int m = 0; m < 4; ++m)
      #pragma unroll
      for (int n = 0; n < 4; ++n)
        acc[m][n] = MFMA(af[m], bfr[n], acc[m][n]);
  }

  #pragma unroll
  for (int m = 0; m < 4; ++m)
    #pragma unroll
    for (int n = 0; n < 4; ++n) {
      const int col = n0 + wc + n*16 + r;
      #pragma unroll
      for (int j = 0; j < 4; ++j) {
        const int row = m0 + wr + m*16 + g*4 + j;
        float v = acc[m][n][j];
        if constexpr (OBF) ((bf16*)Cp)[(size_t)row*N + col] = (bf16)v;
        else               ((float*)Cp)[(size_t)row*N + col] = v;
      }
    }
}

// ---------------- legacy GEMM (f32 inputs, reg-staged): fallback if ws too small ----------------
template<int ABF, int OBF>
__global__ __launch_bounds__(256, 2)
void gemm_nt(const void* __restrict__ Ap, const float* __restrict__ Bp,
             void* __restrict__ Cp, int M, int N, int K) {
  __shared__ bf16 As[2][128][40];
  __shared__ bf16 Bs[2][128][40];
  const int tid = threadIdx.x;
  const int lane = tid & 63, wid = tid >> 6;
  const int m0 = blockIdx.y * 128, n0 = blockIdx.x * 128;
  const int wr = (wid >> 1) * 64, wc = (wid & 1) * 64;
  const int r = lane & 15, g = lane >> 4;
  const float* Af = (const float*)Ap;
  const bf16*  Ab = (const bf16*)Ap;

  f32x4 acc[4][4] = {};
  f32x4 pa[4], pb[4];
  bf16x8 qa[2];
  const int NT = K >> 5;

  auto load_tiles = [&](int kt) {
    const int kk = kt * 32;
    if constexpr (ABF) {
      #pragma unroll
      for (int j = 0; j < 2; ++j) {
        int c = tid + 256*j, row = c >> 2, kc = c & 3;
        qa[j] = *(const bf16x8*)(Ab + (size_t)(m0+row)*K + kk + kc*8);
      }
    } else {
      #pragma unroll
      for (int j = 0; j < 4; ++j) {
        int c = tid + 256*j, row = c >> 3, kc = c & 7;
        pa[j] = *(const f32x4*)(Af + (size_t)(m0+row)*K + kk + kc*4);
      }
    }
    #pragma unroll
    for (int j = 0; j < 4; ++j) {
      int c = tid + 256*j, row = c >> 3, kc = c & 7;
      pb[j] = *(const f32x4*)(Bp + (size_t)(n0+row)*K + kk + kc*4);
    }
  };
  auto write_tiles = [&](int buf) {
    if constexpr (ABF) {
      #pragma unroll
      for (int j = 0; j < 2; ++j) {
        int c = tid + 256*j, row = c >> 2, kc = c & 3;
        *(bf16x8*)&As[buf][row][kc*8] = qa[j];
      }
    } else {
      #pragma unroll
      for (int j = 0; j < 4; ++j) {
        int c = tid + 256*j, row = c >> 3, kc = c & 7;
        bf16x4 b;
        b[0]=(bf16)pa[j][0]; b[1]=(bf16)pa[j][1]; b[2]=(bf16)pa[j][2]; b[3]=(bf16)pa[j][3];
        *(bf16x4*)&As[buf][row][kc*4] = b;
      }
    }
    #pragma unroll
    for (int j = 0; j < 4; ++j) {
      int c = tid + 256*j, row = c >> 3, kc = c & 7;
      bf16x4 b;
      b[0]=(bf16)pb[j][0]; b[1]=(bf16)pb[j][1]; b[2]=(bf16)pb[j][2]; b[3]=(bf16)pb[j][3];
      *(bf16x4*)&Bs[buf][row][kc*4] = b;
    }
  };

  load_tiles(0);
  write_tiles(0);
  __syncthreads();
  for (int kt = 0; kt < NT; ++kt) {
    const int cur = kt & 1;
    if (kt + 1 < NT) load_tiles(kt + 1);
    bf16x8 af[4], bfr[4];
    #pragma unroll
    for (int m = 0; m < 4; ++m) af[m]  = *(const bf16x8*)&As[cur][wr + m*16 + r][g*8];
    #pragma unroll
    for (int n = 0; n < 4; ++n) bfr[n] = *(const bf16x8*)&Bs[cur][wc + n*16 + r][g*8];
    #pragma unroll
    for (int m = 0; m < 4; ++m)
      #pragma unroll
      for (int n = 0; n < 4; ++n)
        acc[m][n] = MFMA(af[m], bfr[n], acc[m][n]);
    if (kt + 1 < NT) write_tiles((kt + 1) & 1);
    __syncthreads();
  }
  #pragma unroll
  for (int m = 0; m < 4; ++m)
    #pragma unroll
    for (int n = 0; n < 4; ++n) {
      const int col = n0 + wc + n*16 + r;
      #pragma unroll
      for (int j = 0; j < 4; ++j) {
        const int row = m0 + wr + m*16 + g*4 + j;
        float v = acc[m][n][j];
        if constexpr (OBF) ((bf16*)Cp)[(size_t)row*N + col] = (bf16)v;
        else               ((float*)Cp)[(size_t)row*N + col] = v;
      }
    }
}

// ---------------- RoPE (interleaved pairs), scale folded in ----------------
__global__ __launch_bounds__(256)
void rope_kernel(bf16* __restrict__ X, const float* __restrict__ F, float scale) {
  const int i = blockIdx.x * 256 + threadIdx.x;
  const size_t e8 = (size_t)i * 8;
  const int t  = (int)(e8 / CC);
  const int c  = (int)(e8 % CC);
  const int hc = c & (DD - 1);
  const float4* f = (const float4*)(F + (size_t)t*256 + (hc>>1)*4);
  bf16x8 v = *(const bf16x8*)(X + e8);
  bf16x8 o;
  #pragma unroll
  for (int p = 0; p < 4; ++p) {
    float x0 = (float)v[2*p], x1 = (float)v[2*p+1];
    float4 ff = f[p];
    o[2*p]   = (bf16)((ff.x*x0 + ff.y*x1) * scale);
    o[2*p+1] = (bf16)((ff.z*x0 + ff.w*x1) * scale);
  }
  *(bf16x8*)(X + e8) = o;
}

// ---------------- V [T][C] -> Vt [H][D][T] per-head transpose ----------------
__global__ __launch_bounds__(256)
void transpose_v(const bf16* __restrict__ V, bf16* __restrict__ Vt) {
  __shared__ bf16 tile[64 * 128];
  const int t0 = blockIdx.x * 64, h = blockIdx.y;
  const int tid = threadIdx.x;
  #pragma unroll
  for (int j = 0; j < 4; ++j) {
    int c = tid + 256*j, t = c >> 4, c16 = c & 15;
    uint4 val = *(const uint4*)(V + (size_t)(t0+t)*CC + h*DD + c16*8);
    int sw = ((t & 7) ^ ((t >> 3) & 7)) << 4;
    *(uint4*)((char*)tile + t*256 + ((c16*16) ^ sw)) = val;
  }
  __syncthreads();
  #pragma unroll
  for (int j = 0; j < 4; ++j) {
    int c = tid + 256*j, d = c >> 3, c8 = c & 7;
    bf16x8 o;
    #pragma unroll
    for (int i = 0; i < 8; ++i) {
      int t = c8*8 + i;
      int sw = ((t & 7) ^ ((t >> 3) & 7)) << 4;
      o[i] = *(const bf16*)((char*)tile + t*256 + ((d*2) ^ sw));
    }
    *(bf16x8*)(Vt + (size_t)(h*DD + d)*TT + t0 + c8*8) = o;
  }
}

// ---------------- Flash attention, swapped-QK 32x32, exp2-domain softmax ----------------
// Block = 4 waves x 32 q-rows = 128 q-rows, one head. KVBLK = 64.
// Q pre-scaled by log2(e)/sqrt(D). K [T][C]; Vt [H][D][T]. O [T][C].
// stage(): global-load + LDS-write ADJACENT (liveness confined). The T14 split
// (loads live across compute) spilled to scratch at this occupancy (R8: 1.6GB
// WRITE_SIZE) -- do not reintroduce. Cross-block TLP hides staging latency.
__global__ __launch_bounds__(256, 3)
void attn_kernel(const bf16* __restrict__ Q, const bf16* __restrict__ Kb,
                 const bf16* __restrict__ Vt, bf16* __restrict__ O) {
  __shared__ bf16 Ks[64 * 128];   // [kv][d], 256B rows, 16-slot XOR swizzle
  __shared__ bf16 Vs[128 * 64];   // [d][kv], 128B rows, 8-slot XOR swizzle

  const int tid = threadIdx.x, lane = tid & 63, wid = tid >> 6;
  const int c31 = lane & 31, g2 = lane >> 5;

  const int bid = blockIdx.x;
  const int fid = (bid & 7) * 96 + (bid >> 3);
  const int h = fid >> 5, qt = fid & 31;
  const int qrow = qt * 128 + wid * 32 + c31;

  bf16x8 aq[8];
  {
    const bf16* qp = Q + (size_t)qrow * CC + h * DD + g2 * 8;
    #pragma unroll
    for (int d0 = 0; d0 < 8; ++d0) aq[d0] = *(const bf16x8*)(qp + d0 * 16);
  }

  float m_ = -1e30f, l_ = 0.f;
  f32x16 o_[4] = {};

  auto stage = [&](int kv0) {
    uint4 kr[4], vr4[4];
    #pragma unroll
    for (int j = 0; j < 4; ++j) {
      int cc = tid + 256*j, row = cc >> 4, c16 = cc & 15;
      kr[j] = *(const uint4*)(Kb + (size_t)(kv0 + row) * CC + h * DD + c16 * 8);
    }
    #pragma unroll
    for (int j = 0; j < 4; ++j) {
      int cc = tid + 256*j, row = cc >> 3, c8 = cc & 7;
      vr4[j] = *(const uint4*)(Vt + (size_t)(h * DD + row) * TT + kv0 + c8 * 8);
    }
    #pragma unroll
    for (int j = 0; j < 4; ++j) {
      int cc = tid + 256*j, row = cc >> 4, c16 = cc & 15;
      *(uint4*)((char*)Ks + row * 256 + ((c16 * 16) ^ ((row & 15) << 4))) = kr[j];
    }
    #pragma unroll
    for (int j = 0; j < 4; ++j) {
      int cc = tid + 256*j, row = cc >> 3, c8 = cc & 7;
      *(uint4*)((char*)Vs + row * 128 + ((c8 * 16) ^ ((row & 7) << 4))) = vr4[j];
    }
  };

  const int NT = TT / 64;
  for (int t = 0; t < NT; ++t) {
    if (t) __syncthreads();        // all waves done reading tile t-1
    stage(t * 64);
    __syncthreads();               // tile t visible

    // S^T = K . Q^T : s[tt][reg] = S[kv = 32tt + (reg&3)+8*(reg>>2)+4*g2][q = c31]
    f32x16 s[2] = {};
    __builtin_amdgcn_s_setprio(1);
    #pragma unroll
    for (int d0 = 0; d0 < 8; ++d0) {
      #pragma unroll
      for (int tt = 0; tt < 2; ++tt) {
        const int kvr = tt * 32 + c31;
        bf16x8 ak = *(const bf16x8*)((const char*)Ks + kvr * 256 +
                                     ((d0 * 32 + g2 * 16) ^ ((kvr & 15) << 4)));
        s[tt] = MFMA32(ak, aq[d0], s[tt]);
      }
    }
    __builtin_amdgcn_s_setprio(0);

    // ---- online softmax (log2 domain), one q-row per lane (partner = lane^32) ----
    float mx = fmaxf(s[0][0], s[0][1]);
    #pragma unroll
    for (int i = 2; i < 16; i += 2) mx = max3f(mx, s[0][i], s[0][i+1]);
    #pragma unroll
    for (int i = 0; i < 16; i += 2) mx = max3f(mx, s[1][i], s[1][i+1]);
    mx = fmaxf(mx, __shfl_xor(mx, 32, 64));
    if (!__all(mx <= m_ + 8.f)) {              // defer-max, THR=8 (log2 units)
      float mn = fmaxf(m_, mx);
      float al = __builtin_amdgcn_exp2f(m_ - mn);
      l_ *= al;
      #pragma unroll
      for (int d0 = 0; d0 < 4; ++d0) o_[d0] *= al;
      m_ = mn;
    }

    // P = exp2(S - m), packed to bf16 pairs via v_cvt_pk_bf16_f32.
    unsigned w0[8], w1[8];
    float rs = 0.f;
    #pragma unroll
    for (int jj = 0; jj < 8; ++jj) {
      float a0 = __builtin_amdgcn_exp2f(s[0][2*jj] - m_);
      float b0 = __builtin_amdgcn_exp2f(s[0][2*jj+1] - m_);
      float a1 = __builtin_amdgcn_exp2f(s[1][2*jj] - m_);
      float b1 = __builtin_amdgcn_exp2f(s[1][2*jj+1] - m_);
      rs += (a0 + b0) + (a1 + b1);
      w0[jj] = cvtpk(a0, b0);
      w1[jj] = cvtpk(a1, b1);
    }
    rs += __shfl_xor(rs, 32, 64);
    l_ += rs;

    // Redistribute P into PV B-fragments via permlane32_swap (no LDS).
    bf16x8 pb[4];
    #pragma unroll
    for (int t2 = 0; t2 < 4; ++t2) {
      const int jA = (t2 & 1) * 4;
      unsigned x0, y0, x1, y1;
      if (t2 < 2) { x0 = w0[jA]; y0 = w0[jA+2]; x1 = w0[jA+1]; y1 = w0[jA+3]; }
      else        { x0 = w1[jA]; y0 = w1[jA+2]; x1 = w1[jA+1]; y1 = w1[jA+3]; }
      plswap(x0, y0);
      plswap(x1, y1);
      uint32x4 uu; uu[0] = x0; uu[1] = x1; uu[2] = y0; uu[3] = y1;
      pb[t2] = __builtin_bit_cast(bf16x8, uu);
    }

    // O^T += V^T . P^T
    __builtin_amdgcn_s_setprio(1);
    #pragma unroll
    for (int d0 = 0; d0 < 4; ++d0) {
      const int vr = d0 * 32 + c31;
      #pragma unroll
      for (int t2 = 0; t2 < 4; ++t2) {
        bf16x8 av = *(const bf16x8*)((const char*)Vs + vr * 128 +
                                     ((t2 * 32 + g2 * 16) ^ ((vr & 7) << 4)));
        o_[d0] = MFMA32(av, pb[t2], o_[d0]);
      }
    }
    __builtin_amdgcn_s_setprio(0);
  }

  const float inv = 1.f / l_;
  bf16* orow = O + (size_t)qrow * CC + h * DD;
  #pragma unroll
  for (int d0 = 0; d0 < 4; ++d0)
    #pragma unroll
    for (int q4 = 0; q4 < 4; ++q4) {
      uint2 val;
      val.x = cvtpk(o_[d0][q4*4 + 0] * inv, o_[d0][q4*4 + 1] * inv);
      val.y = cvtpk(o_[d0][q4*4 + 2] * inv, o_[d0][q4*4 + 3] * inv);
      *(uint2*)(orow + d0*32 + q4*8 + g2*4) = val;
    }
}

// ---------------- host ----------------
extern "C" void kernel_launch(void* const* d_in, const int* in_sizes, int n_in,
                              void* d_out, int out_size, void* d_ws, size_t ws_size,
                              hipStream_t stream) {
  const float* x   = (const float*)d_in[0];
  const float* ctx = (const float*)d_in[1];
  const float* fr  = (const float*)d_in[2];
  const float* Wq  = (const float*)d_in[3];
  const float* Wk  = (const float*)d_in[4];
  const float* Wv  = (const float*)d_in[5];
  const float* Wo  = (const float*)d_in[6];
  float* out = (float*)d_out;
  char* ws = (char*)d_ws;

  const size_t SZ  = (size_t)TT * CC * sizeof(bf16);   // 25,165,824
  const size_t WSZ = (size_t)CC * CC * sizeof(bf16);   // 18,874,368
  bf16* Qb  = (bf16*)(ws);
  bf16* Kbf = (bf16*)(ws + SZ);
  bf16* Vb  = (bf16*)(ws + 2*SZ);
  bf16* Vtb = (bf16*)(ws + 3*SZ);
  bf16* Ob  = Vb;                        // attn output overwrites V (dead after transpose)

  const int rblocks = (TT*CC/8)/256;
  const float QSCALE = 0.12751743314942355f;  // log2(e)/sqrt(128)

  const size_t NEED = 5*SZ + 3*WSZ;      // 182.5 MB
  if (ws_size >= NEED) {
    bf16* xb   = Vtb;                    // x dead after Q-gemm; Vtb written later
    bf16* ctxb = (bf16*)(ws + 4*SZ);
    bf16* Wqb  = (bf16*)(ws + 5*SZ);     // reused for Wo after Q-gemm
    bf16* Wkb  = (bf16*)(ws + 5*SZ + WSZ);
    bf16* Wvb  = (bf16*)(ws + 5*SZ + 2*WSZ);
    bf16* Wob  = Wqb;

    cvt_bf16<<<2048, 256, 0, stream>>>(x,   xb,   TT*CC/8);
    cvt_bf16<<<2048, 256, 0, stream>>>(ctx, ctxb, TT*CC/8);
    cvt_bf16<<<2048, 256, 0, stream>>>(Wq,  Wqb,  CC*CC/8);
    cvt_bf16<<<2048, 256, 0, stream>>>(Wk,  Wkb,  CC*CC/8);
    cvt_bf16<<<2048, 256, 0, stream>>>(Wv,  Wvb,  CC*CC/8);

    dim3 gg(CC/128, TT/128);
    gemm_bt<1><<<gg, 256, 0, stream>>>(xb,   Wqb, Qb,  TT, CC, CC);
    gemm_bt<1><<<gg, 256, 0, stream>>>(ctxb, Wkb, Kbf, TT, CC, CC);
    gemm_bt<1><<<gg, 256, 0, stream>>>(ctxb, Wvb, Vb,  TT, CC, CC);

    rope_kernel<<<rblocks, 256, 0, stream>>>(Qb,  fr, QSCALE);
    rope_kernel<<<rblocks, 256, 0, stream>>>(Kbf, fr, 1.0f);

    transpose_v<<<dim3(TT/64, HH), 256, 0, stream>>>(Vb, Vtb);   // overwrites xb (dead)
    cvt_bf16<<<2048, 256, 0, stream>>>(Wo, Wob, CC*CC/8);        // into Wqb slot (dead)
    attn_kernel<<<dim3(768), 256, 0, stream>>>(Qb, Kbf, Vtb, Ob);

    gemm_bt<0><<<gg, 256, 0, stream>>>(Ob, Wob, out, TT, CC, CC);
  } else {
    // fallback: R7 path (f32 reg-staged GEMMs), ws usage 4*SZ
    dim3 gg(CC/128, TT/128);
    gemm_nt<0,1><<<gg, 256, 0, stream>>>(x,   Wq, Qb,  TT, CC, CC);
    gemm_nt<0,1><<<gg, 256, 0, stream>>>(ctx, Wk, Kbf, TT, CC, CC);
    gemm_nt<0,1><<<gg, 256, 0, stream>>>(ctx, Wv, Vb,  TT, CC, CC);
    rope_kernel<<<rblocks, 256, 0, stream>>>(Qb,  fr, QSCALE);
    rope_kernel<<<rblocks, 256, 0, stream>>>(Kbf, fr, 1.0f);
    transpose_v<<<dim3(TT/64, HH), 256, 0, stream>>>(Vb, Vtb);
    attn_kernel<<<dim3(768), 256, 0, stream>>>(Qb, Kbf, Vtb, Ob);
    gemm_nt<1,0><<<gg, 256, 0, stream>>>(Ob, Wo, out, TT, CC, CC);
  }
}